// Round 14
// baseline (479.839 us; speedup 1.0000x reference)
//
#include <hip/hip_runtime.h>
#include <math.h>

// Greedy farthest-point selection via precomputed Gram triangle.
// kgram512: R9's 64x64-tile double-buffered f16-split MFMA engine, widened to
//           512 threads / 8 waves per block (each wave a 32x16 quadrant,
//           2x1 frags, 6 MFMAs/chunk). Same LDS (4 blocks/CU) -> 32 waves/CU
//           (2x R9) to cover the barrier/ds_read/MFMA stall chains that
//           capped every prior variant at ~160us. Numerics bit-identical to
//           R9 (same split, same k-map, same per-chunk product order).
// kfused  : L2-prefetch of the batch's G triangle (180KB -> local XCD L2,
//           16 blocks x 180KB = 2.9MB < 4MB), then the proven serial
//           argmin (wave 0) + gather (all waves).
// G stride padded to TRIP=45152 (16B alignment for float4 prefetch).
// Fallback (small ws): split path, G in out_v region.

constexpr int BB = 128, NN = 300, DV = 1024, DA = 128, KK = 64;
constexpr int TRI  = NN * (NN + 1) / 2;       // 45150
constexpr int TRIP = 45152;                   // padded batch stride (16B align)
constexpr int TB = 64;
constexpr int NTILES = 15;
constexpr int KC = 32;
constexpr int NCH = DV / KC;                  // 32 chunks
constexpr int LDH = 36;                       // f16 row stride: 72 B

__device__ __constant__ int c_ib[NTILES] = {0,0,0,0,0, 1,1,1,1, 2,2,2, 3,3, 4};
__device__ __constant__ int c_jb[NTILES] = {0,1,2,3,4, 1,2,3,4, 2,3,4, 3,4, 4};

typedef _Float16 f16x8 __attribute__((ext_vector_type(8)));
typedef float    f32x4 __attribute__((ext_vector_type(4)));

union H4 { _Float16 h[4]; uint2 u; };
union F8 { uint2 u2[2]; f16x8 v; };

__device__ __forceinline__ int tri_base(int i) { return i * NN - (i * (i - 1)) / 2; }

// ---------------- 1. kgram512: 64-tile, dbuf, 8 waves ----------------
// Grid 1920 = 15 tiles x 128 batches, XCD-swizzled (16 batches/XCD).
__global__ __launch_bounds__(512) void kgram512(const float* __restrict__ video,
                                                float* __restrict__ G) {
    const int bid  = blockIdx.x;
    const int swz  = (bid & 7) * 240 + (bid >> 3);      // bijective: 1920=8*240
    const int batch = swz / 15;
    const int tile  = swz - batch * 15;
    const int i0 = c_ib[tile] * TB, j0 = c_jb[tile] * TB;
    const bool diag = (i0 == j0);
    const int tid = threadIdx.x;

    __shared__ _Float16 sH[2][4][TB][LDH];   // [buf][A-hi,A-lo,B-hi,B-lo] 36.9KB
    __shared__ float    s_part[512];
    __shared__ double   s_inv[2][TB];

    const float* vb = video + (size_t)batch * NN * DV;

    // staging role: 4 threads per row (part), 128 rows (A64 + B64)
    const int slab = tid >> 8;               // 0=A(i-rows), 1=B(j-rows)
    const int st   = tid & 255;
    const int lrow = st >> 2;                // 0..63
    const int part = st & 3;                 // quarter of the 32-float chunk
    const int grow = (slab ? j0 : i0) + lrow;
    const bool rok = grow < NN;
    const bool stage_on = !(diag && slab == 1);   // diag: B slab = A slab
    const float4* srcb4 = (const float4*)(vb + (size_t)(rok ? grow : 0) * DV);
    const int qbase = part * 2;              // first float4 index within chunk

    // compute role: wave w -> 32x16 quadrant (wr3 = w>>2, wc3 = w&3)
    const int lane = tid & 63, w = tid >> 6;
    const int wr3 = w >> 2, wc3 = w & 3;
    const int g = lane >> 4, c16 = lane & 15;
    const int bplane = diag ? 0 : 2;

    f32x4 acc[2];
    acc[0] = (f32x4){0.f, 0.f, 0.f, 0.f};
    acc[1] = (f32x4){0.f, 0.f, 0.f, 0.f};

    float ps = 0.f;
    float4 ld[2];
    const float4 z4 = make_float4(0.f, 0.f, 0.f, 0.f);

    auto stage_write = [&](int bf) {
        #pragma unroll
        for (int q = 0; q < 2; ++q) {
            float4 v = ld[q];
            ps = fmaf(v.x, v.x, fmaf(v.y, v.y, fmaf(v.z, v.z, fmaf(v.w, v.w, ps))));
            H4 hi, lo;
            _Float16 h0 = (_Float16)v.x, h1 = (_Float16)v.y,
                     h2 = (_Float16)v.z, h3 = (_Float16)v.w;
            hi.h[0] = h0; hi.h[1] = h1; hi.h[2] = h2; hi.h[3] = h3;
            lo.h[0] = (_Float16)(v.x - (float)h0);
            lo.h[1] = (_Float16)(v.y - (float)h1);
            lo.h[2] = (_Float16)(v.z - (float)h2);
            lo.h[3] = (_Float16)(v.w - (float)h3);
            const int p = part * 8 + 4 * q;              // linear source k
            *(uint2*)&sH[bf][slab * 2 + 0][lrow][p] = hi.u;
            *(uint2*)&sH[bf][slab * 2 + 1][lrow][p] = lo.u;
        }
    };

    // prologue: chunk 0 staged into buf 0; chunk 1 in regs
    if (stage_on) {
        ld[0] = rok ? srcb4[qbase] : z4;
        ld[1] = rok ? srcb4[qbase + 1] : z4;
        stage_write(0);
        ld[0] = rok ? srcb4[8 + qbase] : z4;
        ld[1] = rok ? srcb4[8 + qbase + 1] : z4;
    }
    __syncthreads();

    for (int kc = 0; kc < NCH; ++kc) {
        const int cur = kc & 1, nxt = cur ^ 1;

        if (stage_on && kc < NCH - 1) stage_write(nxt);
        if (stage_on && kc < NCH - 2) {
            ld[0] = rok ? srcb4[(kc + 2) * 8 + qbase] : z4;
            ld[1] = rok ? srcb4[(kc + 2) * 8 + qbase + 1] : z4;
        }

        // compute: 2x1 frags (dual-b64 conflict-free reads, R5-proven geometry)
        f16x8 Ah[2], Al[2], Bh, Bl;
        #pragma unroll
        for (int fr = 0; fr < 2; ++fr) {
            const int row = 32 * wr3 + 16 * fr + c16;
            F8 t;
            t.u2[0] = *(const uint2*)&sH[cur][0][row][4 * g];
            t.u2[1] = *(const uint2*)&sH[cur][0][row][16 + 4 * g];
            Ah[fr] = t.v;
            t.u2[0] = *(const uint2*)&sH[cur][1][row][4 * g];
            t.u2[1] = *(const uint2*)&sH[cur][1][row][16 + 4 * g];
            Al[fr] = t.v;
        }
        {
            const int row = 16 * wc3 + c16;
            F8 t;
            t.u2[0] = *(const uint2*)&sH[cur][bplane + 0][row][4 * g];
            t.u2[1] = *(const uint2*)&sH[cur][bplane + 0][row][16 + 4 * g];
            Bh = t.v;
            t.u2[0] = *(const uint2*)&sH[cur][bplane + 1][row][4 * g];
            t.u2[1] = *(const uint2*)&sH[cur][bplane + 1][row][16 + 4 * g];
            Bl = t.v;
        }
        #pragma unroll
        for (int fr = 0; fr < 2; ++fr) {
            acc[fr] = __builtin_amdgcn_mfma_f32_16x16x32_f16(Ah[fr], Bh, acc[fr], 0, 0, 0);
            acc[fr] = __builtin_amdgcn_mfma_f32_16x16x32_f16(Ah[fr], Bl, acc[fr], 0, 0, 0);
            acc[fr] = __builtin_amdgcn_mfma_f32_16x16x32_f16(Al[fr], Bh, acc[fr], 0, 0, 0);
        }

        __syncthreads();   // one barrier per chunk (dbuf)
    }

    // ---- norms (4 partials per row) ----
    s_part[tid] = ps;
    __syncthreads();
    if (tid < 128) {
        const int sl = tid >> 6, r = tid & 63;
        const int src = (sl && !diag) ? 256 + 4 * r : 4 * r;  // diag: reuse A
        float ssum = s_part[src] + s_part[src + 1] + s_part[src + 2] + s_part[src + 3];
        s_inv[sl][r] = 1.0 / (sqrt((double)ssum) + 1e-5);
    }
    __syncthreads();

    float* Gb = G + (size_t)batch * TRIP;
    #pragma unroll
    for (int fr = 0; fr < 2; ++fr)
        #pragma unroll
        for (int reg = 0; reg < 4; ++reg) {
            const int il = 32 * wr3 + 16 * fr + 4 * g + reg;  // D row (m89)
            const int jl = 16 * wc3 + c16;                    // D col (m89)
            const int i = i0 + il, j = j0 + jl;
            if (i <= j && j < NN)
                Gb[tri_base(i) + (j - i)] =
                    (float)(fabs((double)acc[fr][reg]) * s_inv[0][il] * s_inv[1][jl]);
        }
}

// ---- device helper: greedy selection for one batch, one wave ----
__device__ __forceinline__ void select_wave_tri(const float* __restrict__ Gb,
                                                int lane, int* s_sorted) {
    float best[5];
    int myidx = 0;

    #pragma unroll
    for (int q = 0; q < 5; ++q) {
        int r = lane + 64 * q;
        best[q] = (r < NN) ? Gb[r] : 3.4e38f;
    }

    int last;
    {
        float v = INFINITY; int ri = 1 << 30;
        #pragma unroll
        for (int q = 0; q < 5; ++q)
            if (best[q] < v) { v = best[q]; ri = lane + 64 * q; }
        #pragma unroll
        for (int off = 32; off >= 1; off >>= 1) {
            float ov = __shfl_xor(v, off, 64); int oi = __shfl_xor(ri, off, 64);
            if (ov < v || (ov == v && oi < ri)) { v = ov; ri = oi; }
        }
        last = ri;
    }
    if (lane == 1) myidx = last;

    for (int t = 2; t < KK; ++t) {
        #pragma unroll
        for (int q = 0; q < 5; ++q) {
            int r = lane + 64 * q;
            if (r < NN) {
                int i = min(last, r), j = max(last, r);
                best[q] = fmaxf(best[q], Gb[tri_base(i) + (j - i)]);
            }
        }
        float v = INFINITY; int ri = 1 << 30;
        #pragma unroll
        for (int q = 0; q < 5; ++q)
            if (best[q] < v) { v = best[q]; ri = lane + 64 * q; }
        #pragma unroll
        for (int off = 32; off >= 1; off >>= 1) {
            float ov = __shfl_xor(v, off, 64); int oi = __shfl_xor(ri, off, 64);
            if (ov < v || (ov == v && oi < ri)) { v = ov; ri = oi; }
        }
        last = ri;
        if (lane == t) myidx = last;
    }

    int rank = 0;
    for (int j = 0; j < KK; ++j) {
        int oj = __shfl(myidx, j, 64);
        rank += (oj < myidx) || (oj == myidx && j < lane);
    }
    s_sorted[rank] = myidx;
}

// ---------------- 2. fused selection + gather, with L2 prefetch ----------
__global__ __launch_bounds__(256) void kfused(const float* __restrict__ G,
                                              const float* __restrict__ video,
                                              const float* __restrict__ audio,
                                              float* __restrict__ out_v,
                                              float* __restrict__ out_a) {
    const int b = blockIdx.x, tid = threadIdx.x;
    __shared__ int s_sorted[KK];

    const float* Gb = G + (size_t)b * TRIP;

    // ---- prefetch the whole triangle into this XCD's L2 (2.9MB/XCD) ----
    {
        const float4* G4 = (const float4*)Gb;
        float s = 0.f;
        for (int t = tid; t < TRIP / 4; t += 256) {
            float4 v = G4[t];
            s += v.x + v.y + v.z + v.w;
        }
        asm volatile("" :: "v"(s));     // keep loads live (no DCE)
    }
    __syncthreads();

    if (tid < 64)
        select_wave_tri(Gb, tid, s_sorted);
    __syncthreads();

    const float4* vb4 = (const float4*)(video + (size_t)b * NN * DV);
    float4* ov4 = (float4*)(out_v + (size_t)b * KK * DV);
    #pragma unroll 4
    for (int t = tid; t < KK * DV / 4; t += 256) {
        int k = t >> 8, c = t & 255;
        ov4[t] = vb4[s_sorted[k] * (DV / 4) + c];
    }
    const float4* ab4 = (const float4*)(audio + (size_t)b * NN * DA);
    float4* oa4 = (float4*)(out_a + (size_t)b * KK * DA);
    for (int t = tid; t < KK * DA / 4; t += 256) {
        int k = t >> 5, c = t & 31;
        oa4[t] = ab4[s_sorted[k] * (DA / 4) + c];
    }
}

// ---------------- fallback split path (G in out_v region) ----------------
__global__ __launch_bounds__(64) void kselect(const float* __restrict__ G,
                                              float* __restrict__ out_a) {
    __shared__ int s_sorted[KK];
    select_wave_tri(G + (size_t)blockIdx.x * TRIP, threadIdx.x, s_sorted);
    __syncthreads();
    ((int*)(out_a + (size_t)blockIdx.x * KK * DA))[threadIdx.x] = s_sorted[threadIdx.x];
}

__global__ __launch_bounds__(256) void kgather(const float* __restrict__ video,
                                               const float* __restrict__ audio,
                                               float* __restrict__ out_v,
                                               float* __restrict__ out_a) {
    int b = blockIdx.x, tid = threadIdx.x;
    __shared__ int s_idx[KK];
    const int* idxp = (const int*)(out_a + (size_t)b * KK * DA);
    if (tid < KK) s_idx[tid] = idxp[tid];
    __syncthreads();

    const float4* vb4 = (const float4*)(video + (size_t)b * NN * DV);
    float4* ov4 = (float4*)(out_v + (size_t)b * KK * DV);
    #pragma unroll 4
    for (int t = tid; t < KK * DV / 4; t += 256) {
        int k = t >> 8, c = t & 255;
        ov4[t] = vb4[s_idx[k] * (DV / 4) + c];
    }
    const float4* ab4 = (const float4*)(audio + (size_t)b * NN * DA);
    float4* oa4 = (float4*)(out_a + (size_t)b * KK * DA);
    for (int t = tid; t < KK * DA / 4; t += 256) {
        int k = t >> 5, c = t & 31;
        oa4[t] = ab4[s_idx[k] * (DA / 4) + c];
    }
}

extern "C" void kernel_launch(void* const* d_in, const int* in_sizes, int n_in,
                              void* d_out, int out_size, void* d_ws, size_t ws_size,
                              hipStream_t stream) {
    const float* video = (const float*)d_in[0];
    const float* audio = (const float*)d_in[1];
    float* out   = (float*)d_out;
    float* out_v = out;
    float* out_a = out + (size_t)BB * KK * DV;

    const size_t g_bytes = (size_t)BB * TRIP * sizeof(float);   // 23.1 MB

    if (ws_size >= g_bytes) {
        float* G = (float*)d_ws;
        kgram512<<<NTILES * BB, 512, 0, stream>>>(video, G);
        kfused  <<<BB, 256, 0, stream>>>(G, video, audio, out_v, out_a);
    } else {
        // G in out_v region: selection reads complete before gather writes
        // (separate kernels serialize on the stream).
        float* G = out;
        kgram512<<<NTILES * BB, 512, 0, stream>>>(video, G);
        kselect <<<BB, 64, 0, stream>>>(G, out_a);
        kgather <<<BB, 256, 0, stream>>>(video, audio, out_v, out_a);
    }
}

// Round 15
// 207.275 us; speedup vs baseline: 2.3150x; 2.3150x over previous
//
#include <hip/hip_runtime.h>
#include <math.h>

// Greedy farthest-point selection via precomputed Gram triangle.
// kgram : R9's proven engine — 64x64-tile MFMA f16 2-way split (RNE hi + lo
//         residual, 3 cross-products, f32 accum), double-buffered LDS (one
//         barrier/chunk), dual-b64 conflict-free fragment reads, reg prefetch
//         2 chunks ahead, XCD-swizzled (batch b -> XCD b/16's L2).
// kfused: selection+gather, block->batch remapped so batch b's selection runs
//         on XCD b/16 — the XCD whose L2 holds its G triangle (the serial
//         63-step argmin chain then pays L2 (~250cy) not L3 (~700cy) per step).
// Fallback (tiny ws): split path, G in out_v region (kernels serialize).

constexpr int BB = 128, NN = 300, DV = 1024, DA = 128, KK = 64;
constexpr int TRI = NN * (NN + 1) / 2;        // 45150
constexpr int TB = 64;
constexpr int NTILES = 15;
constexpr int KC = 32;
constexpr int NCH = DV / KC;                  // 32 chunks
constexpr int LDH = 36;                       // f16 row stride: 72 B

__device__ __constant__ int c_ib[NTILES] = {0,0,0,0,0, 1,1,1,1, 2,2,2, 3,3, 4};
__device__ __constant__ int c_jb[NTILES] = {0,1,2,3,4, 1,2,3,4, 2,3,4, 3,4, 4};

typedef _Float16 f16x8 __attribute__((ext_vector_type(8)));
typedef float    f32x4 __attribute__((ext_vector_type(4)));

union H4 { _Float16 h[4]; uint2 u; };
union F8 { uint2 u2[2]; f16x8 v; };

__device__ __forceinline__ int tri_base(int i) { return i * NN - (i * (i - 1)) / 2; }

// ---------------- 1. kgram: 64-tile, dbuf, 4 waves (R9-proven) ----------------
__global__ __launch_bounds__(256) void kgram(const float* __restrict__ video,
                                             float* __restrict__ G) {
    const int bid  = blockIdx.x;
    const int swz  = (bid & 7) * 240 + (bid >> 3);      // bijective: 1920=8*240
    const int batch = swz / 15;
    const int tile  = swz - batch * 15;
    const int i0 = c_ib[tile] * TB, j0 = c_jb[tile] * TB;
    const bool diag = (i0 == j0);
    const int tid = threadIdx.x;

    __shared__ _Float16 sH[2][4][TB][LDH];   // [buf][A-hi,A-lo,B-hi,B-lo] 36.9 KB
    __shared__ float    s_part[256];
    __shared__ double   s_inv[2][TB];

    const float* vb = video + (size_t)batch * NN * DV;

    // staging role: thread -> (slab, row, k-half); 16 floats per chunk
    const int slab  = tid >> 7;           // 0=A(i-rows), 1=B(j-rows)
    const int lrow  = (tid >> 1) & 63;
    const int khalf = tid & 1;
    const int grow  = (slab ? j0 : i0) + lrow;
    const bool rok  = grow < NN;
    const bool stage_on = !(diag && slab == 1);   // diag: B slab = A slab
    const float4* srcb4 = (const float4*)(vb + (size_t)(rok ? grow : 0) * DV);
    const int qbase = khalf * 4;          // float4 index within chunk

    // compute role
    const int lane = tid & 63, w = tid >> 6;
    const int wr = w >> 1, wc = w & 1;
    const int g = lane >> 4, c16 = lane & 15;
    const int bplane = diag ? 0 : 2;

    f32x4 acc[2][2];
    #pragma unroll
    for (int fr = 0; fr < 2; ++fr)
        #pragma unroll
        for (int fc = 0; fc < 2; ++fc) acc[fr][fc] = (f32x4){0.f, 0.f, 0.f, 0.f};

    float ps = 0.f;
    float4 ld[4];
    const float4 z4 = make_float4(0.f, 0.f, 0.f, 0.f);

    auto stage_write = [&](int bf) {
        #pragma unroll
        for (int q = 0; q < 4; ++q) {
            float4 v = ld[q];
            ps = fmaf(v.x, v.x, fmaf(v.y, v.y, fmaf(v.z, v.z, fmaf(v.w, v.w, ps))));
            H4 hi, lo;
            _Float16 h0 = (_Float16)v.x, h1 = (_Float16)v.y,
                     h2 = (_Float16)v.z, h3 = (_Float16)v.w;
            hi.h[0] = h0; hi.h[1] = h1; hi.h[2] = h2; hi.h[3] = h3;
            lo.h[0] = (_Float16)(v.x - (float)h0);
            lo.h[1] = (_Float16)(v.y - (float)h1);
            lo.h[2] = (_Float16)(v.z - (float)h2);
            lo.h[3] = (_Float16)(v.w - (float)h3);
            const int p = khalf * 16 + 4 * q;            // linear source k
            *(uint2*)&sH[bf][slab * 2 + 0][lrow][p] = hi.u;
            *(uint2*)&sH[bf][slab * 2 + 1][lrow][p] = lo.u;
        }
    };

    // prologue: chunk 0 staged into buf 0; chunk 1 in regs
    if (stage_on) {
        #pragma unroll
        for (int q = 0; q < 4; ++q) ld[q] = rok ? srcb4[qbase + q] : z4;
        stage_write(0);
        #pragma unroll
        for (int q = 0; q < 4; ++q) ld[q] = rok ? srcb4[8 + qbase + q] : z4;
    }
    __syncthreads();

    for (int kc = 0; kc < NCH; ++kc) {
        const int cur = kc & 1, nxt = cur ^ 1;

        if (stage_on && kc < NCH - 1) stage_write(nxt);
        if (stage_on && kc < NCH - 2) {
            #pragma unroll
            for (int q = 0; q < 4; ++q)
                ld[q] = rok ? srcb4[(kc + 2) * 8 + qbase + q] : z4;
        }

        f16x8 Ah[2], Al[2], Bh[2], Bl[2];
        #pragma unroll
        for (int fr = 0; fr < 2; ++fr) {
            const int row = 32 * wr + 16 * fr + c16;
            F8 t;
            t.u2[0] = *(const uint2*)&sH[cur][0][row][4 * g];
            t.u2[1] = *(const uint2*)&sH[cur][0][row][16 + 4 * g];
            Ah[fr] = t.v;
            t.u2[0] = *(const uint2*)&sH[cur][1][row][4 * g];
            t.u2[1] = *(const uint2*)&sH[cur][1][row][16 + 4 * g];
            Al[fr] = t.v;
        }
        #pragma unroll
        for (int fc = 0; fc < 2; ++fc) {
            const int row = 32 * wc + 16 * fc + c16;
            F8 t;
            t.u2[0] = *(const uint2*)&sH[cur][bplane + 0][row][4 * g];
            t.u2[1] = *(const uint2*)&sH[cur][bplane + 0][row][16 + 4 * g];
            Bh[fc] = t.v;
            t.u2[0] = *(const uint2*)&sH[cur][bplane + 1][row][4 * g];
            t.u2[1] = *(const uint2*)&sH[cur][bplane + 1][row][16 + 4 * g];
            Bl[fc] = t.v;
        }
        #pragma unroll
        for (int fr = 0; fr < 2; ++fr)
            #pragma unroll
            for (int fc = 0; fc < 2; ++fc) {
                acc[fr][fc] = __builtin_amdgcn_mfma_f32_16x16x32_f16(Ah[fr], Bh[fc], acc[fr][fc], 0, 0, 0);
                acc[fr][fc] = __builtin_amdgcn_mfma_f32_16x16x32_f16(Ah[fr], Bl[fc], acc[fr][fc], 0, 0, 0);
                acc[fr][fc] = __builtin_amdgcn_mfma_f32_16x16x32_f16(Al[fr], Bh[fc], acc[fr][fc], 0, 0, 0);
            }

        __syncthreads();   // one barrier per chunk: nxt fully staged, cur consumed
    }

    // ---- norms ----
    s_part[tid] = ps;
    __syncthreads();
    if (tid < 128) {
        const int sl = tid >> 6, r = tid & 63;
        const int src = (sl && !diag) ? 128 + 2 * r : 2 * r;   // diag: reuse A
        float ssum = s_part[src] + s_part[src + 1];
        s_inv[sl][r] = 1.0 / (sqrt((double)ssum) + 1e-5);
    }
    __syncthreads();

    float* Gb = G + (size_t)batch * TRI;
    #pragma unroll
    for (int fr = 0; fr < 2; ++fr)
        #pragma unroll
        for (int fc = 0; fc < 2; ++fc)
            #pragma unroll
            for (int reg = 0; reg < 4; ++reg) {
                const int il = 32 * wr + 16 * fr + 4 * g + reg;   // D row (m89)
                const int jl = 32 * wc + 16 * fc + c16;           // D col (m89)
                const int i = i0 + il, j = j0 + jl;
                if (i <= j && j < NN)
                    Gb[tri_base(i) + (j - i)] =
                        (float)(fabs((double)acc[fr][fc][reg]) * s_inv[0][il] * s_inv[1][jl]);
            }
}

// ---- device helper: greedy selection for one batch, one wave ----
__device__ __forceinline__ void select_wave_tri(const float* __restrict__ Gb,
                                                int lane, int* s_sorted) {
    float best[5];
    int myidx = 0;

    #pragma unroll
    for (int q = 0; q < 5; ++q) {
        int r = lane + 64 * q;
        best[q] = (r < NN) ? Gb[r] : 3.4e38f;
    }

    int last;
    {
        float v = INFINITY; int ri = 1 << 30;
        #pragma unroll
        for (int q = 0; q < 5; ++q)
            if (best[q] < v) { v = best[q]; ri = lane + 64 * q; }
        #pragma unroll
        for (int off = 32; off >= 1; off >>= 1) {
            float ov = __shfl_xor(v, off, 64); int oi = __shfl_xor(ri, off, 64);
            if (ov < v || (ov == v && oi < ri)) { v = ov; ri = oi; }
        }
        last = ri;
    }
    if (lane == 1) myidx = last;

    for (int t = 2; t < KK; ++t) {
        #pragma unroll
        for (int q = 0; q < 5; ++q) {
            int r = lane + 64 * q;
            if (r < NN) {
                int i = min(last, r), j = max(last, r);
                best[q] = fmaxf(best[q], Gb[tri_base(i) + (j - i)]);
            }
        }
        float v = INFINITY; int ri = 1 << 30;
        #pragma unroll
        for (int q = 0; q < 5; ++q)
            if (best[q] < v) { v = best[q]; ri = lane + 64 * q; }
        #pragma unroll
        for (int off = 32; off >= 1; off >>= 1) {
            float ov = __shfl_xor(v, off, 64); int oi = __shfl_xor(ri, off, 64);
            if (ov < v || (ov == v && oi < ri)) { v = ov; ri = oi; }
        }
        last = ri;
        if (lane == t) myidx = last;
    }

    int rank = 0;
    for (int j = 0; j < KK; ++j) {
        int oj = __shfl(myidx, j, 64);
        rank += (oj < myidx) || (oj == myidx && j < lane);
    }
    s_sorted[rank] = myidx;
}

// ---------------- 2. fused selection + gather, XCD-aligned ----------------
// Block bid runs on XCD bid%8 (round-robin heuristic); kgram put batch b's
// G triangle in XCD (b/16)'s L2. Map bid -> batch = (bid&7)*16 + (bid>>3)
// so the selection chain reads its own XCD's L2. Bijective over 128.
__global__ __launch_bounds__(256) void kfused(const float* __restrict__ G,
                                              const float* __restrict__ video,
                                              const float* __restrict__ audio,
                                              float* __restrict__ out_v,
                                              float* __restrict__ out_a) {
    const int b = (blockIdx.x & 7) * 16 + (blockIdx.x >> 3);
    const int tid = threadIdx.x;
    __shared__ int s_sorted[KK];

    if (tid < 64)
        select_wave_tri(G + (size_t)b * TRI, tid, s_sorted);
    __syncthreads();

    const float4* vb4 = (const float4*)(video + (size_t)b * NN * DV);
    float4* ov4 = (float4*)(out_v + (size_t)b * KK * DV);
    #pragma unroll 4
    for (int t = tid; t < KK * DV / 4; t += 256) {
        int k = t >> 8, c = t & 255;
        ov4[t] = vb4[s_sorted[k] * (DV / 4) + c];
    }
    const float4* ab4 = (const float4*)(audio + (size_t)b * NN * DA);
    float4* oa4 = (float4*)(out_a + (size_t)b * KK * DA);
    for (int t = tid; t < KK * DA / 4; t += 256) {
        int k = t >> 5, c = t & 31;
        oa4[t] = ab4[s_sorted[k] * (DA / 4) + c];
    }
}

// ---------------- fallback split path (G in out_v region) ----------------
__global__ __launch_bounds__(64) void kselect(const float* __restrict__ G,
                                              float* __restrict__ out_a) {
    __shared__ int s_sorted[KK];
    select_wave_tri(G + (size_t)blockIdx.x * TRI, threadIdx.x, s_sorted);
    __syncthreads();
    ((int*)(out_a + (size_t)blockIdx.x * KK * DA))[threadIdx.x] = s_sorted[threadIdx.x];
}

__global__ __launch_bounds__(256) void kgather(const float* __restrict__ video,
                                               const float* __restrict__ audio,
                                               float* __restrict__ out_v,
                                               float* __restrict__ out_a) {
    int b = blockIdx.x, tid = threadIdx.x;
    __shared__ int s_idx[KK];
    const int* idxp = (const int*)(out_a + (size_t)b * KK * DA);
    if (tid < KK) s_idx[tid] = idxp[tid];
    __syncthreads();

    const float4* vb4 = (const float4*)(video + (size_t)b * NN * DV);
    float4* ov4 = (float4*)(out_v + (size_t)b * KK * DV);
    #pragma unroll 4
    for (int t = tid; t < KK * DV / 4; t += 256) {
        int k = t >> 8, c = t & 255;
        ov4[t] = vb4[s_idx[k] * (DV / 4) + c];
    }
    const float4* ab4 = (const float4*)(audio + (size_t)b * NN * DA);
    float4* oa4 = (float4*)(out_a + (size_t)b * KK * DA);
    for (int t = tid; t < KK * DA / 4; t += 256) {
        int k = t >> 5, c = t & 31;
        oa4[t] = ab4[s_idx[k] * (DA / 4) + c];
    }
}

extern "C" void kernel_launch(void* const* d_in, const int* in_sizes, int n_in,
                              void* d_out, int out_size, void* d_ws, size_t ws_size,
                              hipStream_t stream) {
    const float* video = (const float*)d_in[0];
    const float* audio = (const float*)d_in[1];
    float* out   = (float*)d_out;
    float* out_v = out;
    float* out_a = out + (size_t)BB * KK * DV;

    const size_t g_bytes = (size_t)BB * TRI * sizeof(float);   // 23.1 MB

    if (ws_size >= g_bytes) {
        float* G = (float*)d_ws;
        kgram <<<NTILES * BB, 256, 0, stream>>>(video, G);
        kfused<<<BB, 256, 0, stream>>>(G, video, audio, out_v, out_a);
    } else {
        float* G = out;
        kgram  <<<NTILES * BB, 256, 0, stream>>>(video, G);
        kselect<<<BB, 64, 0, stream>>>(G, out_a);
        kgather<<<BB, 256, 0, stream>>>(video, audio, out_v, out_a);
    }
}